// Round 6
// baseline (673.662 us; speedup 1.0000x reference)
//
#include <hip/hip_runtime.h>
#include <math.h>

#define D 128
#define H 8
#define HD 16

typedef __attribute__((ext_vector_type(8))) short bf16x8;
typedef __attribute__((ext_vector_type(4))) float f32x4;

__device__ __forceinline__ ushort f2bf(float x) {
    union { float f; unsigned u; } v; v.f = x;
    unsigned r = v.u + 0x7fffu + ((v.u >> 16) & 1u);   // RNE
    return (ushort)(r >> 16);
}
__device__ __forceinline__ float bflo(unsigned u) {
    union { unsigned u; float f; } x; x.u = u << 16; return x.f;
}
__device__ __forceinline__ float bfhi(unsigned u) {
    union { unsigned u; float f; } x; x.u = u & 0xffff0000u; return x.f;
}
__device__ __forceinline__ float bf2f(short s) {
    union { unsigned u; float f; } x; x.u = ((unsigned)(ushort)s) << 16; return x.f;
}

__device__ __forceinline__ float dot16(const float* qf, uint4 a, uint4 b) {
    float w;
    w  = qf[0]  * bflo(a.x) + qf[1]  * bfhi(a.x);
    w += qf[2]  * bflo(a.y) + qf[3]  * bfhi(a.y);
    w += qf[4]  * bflo(a.z) + qf[5]  * bfhi(a.z);
    w += qf[6]  * bflo(a.w) + qf[7]  * bfhi(a.w);
    w += qf[8]  * bflo(b.x) + qf[9]  * bfhi(b.x);
    w += qf[10] * bflo(b.y) + qf[11] * bfhi(b.y);
    w += qf[12] * bflo(b.z) + qf[13] * bfhi(b.z);
    w += qf[14] * bflo(b.w) + qf[15] * bfhi(b.w);
    return w;
}
__device__ __forceinline__ void acc16(float* num, float e, uint4 a, uint4 b) {
    num[0]  = fmaf(e, bflo(a.x), num[0]);  num[1]  = fmaf(e, bfhi(a.x), num[1]);
    num[2]  = fmaf(e, bflo(a.y), num[2]);  num[3]  = fmaf(e, bfhi(a.y), num[3]);
    num[4]  = fmaf(e, bflo(a.z), num[4]);  num[5]  = fmaf(e, bfhi(a.z), num[5]);
    num[6]  = fmaf(e, bflo(a.w), num[6]);  num[7]  = fmaf(e, bfhi(a.w), num[7]);
    num[8]  = fmaf(e, bflo(b.x), num[8]);  num[9]  = fmaf(e, bfhi(b.x), num[9]);
    num[10] = fmaf(e, bflo(b.y), num[10]); num[11] = fmaf(e, bfhi(b.y), num[11]);
    num[12] = fmaf(e, bflo(b.z), num[12]); num[13] = fmaf(e, bfhi(b.z), num[13]);
    num[14] = fmaf(e, bflo(b.w), num[14]); num[15] = fmaf(e, bfhi(b.w), num[15]);
}

// ---------------------------------------------------------------------------
// bf16 MFMA GEMM. Block = 4 waves, covers 32 rows; wave w handles cols
// [w*MW,(w+1)*MW). Two A-strips/wave so every B-load feeds 2 MFMAs.
// AMODE: 0 = A bf16; 1 = A fp32 (convert on load).
// EPI:   0 = bias -> bf16; 5 = bias + bf16 residual (extra) -> bf16.
// WRITEA: wave 0 writes its converted A-frags to abf (bf16 mirror of A).
// STATF: epilogue accumulates per-column sum/sumsq of the fp32 outputs into
//        ostats (atomics) and the LAST block finalizes scale/shift
//        (ostats[256+j], ostats[384+j]) from g/bb — replaces bn_stats+finalize.
// ---------------------------------------------------------------------------
template<int AMODE, int EPI, int K, int MW, bool WRITEA, bool STATF>
__global__ __launch_bounds__(256)
void gemm_v2_kernel(const void* __restrict__ Ap,
                    const ushort* __restrict__ W,
                    const float* __restrict__ bias,
                    const void* __restrict__ extra,
                    ushort* __restrict__ outb,
                    ushort* __restrict__ abf,
                    float* __restrict__ ostats, int* __restrict__ ticket,
                    const float* __restrict__ g, const float* __restrict__ bb,
                    int N)
{
    constexpr int M  = MW * 4;
    constexpr int KT = K / 32;

    const int lane = threadIdx.x & 63, wave = threadIdx.x >> 6;
    const int lr = lane & 15, lq = lane >> 4;
    const int row0 = blockIdx.x * 32;
    const int c0w  = wave * MW;

    int ar0 = min(row0 + lr, N - 1);
    int ar1 = min(row0 + 16 + lr, N - 1);

    bf16x8 afr[2][KT];
    #pragma unroll
    for (int s = 0; s < 2; ++s) {
        int ar = s ? ar1 : ar0;
        if (AMODE == 0) {
            const ushort* ap = (const ushort*)Ap + (size_t)ar * K + lq * 8;
            #pragma unroll
            for (int t = 0; t < KT; ++t) afr[s][t] = *(const bf16x8*)(ap + t * 32);
        } else {
            const float* ap = (const float*)Ap + (size_t)ar * K + lq * 8;
            #pragma unroll
            for (int t = 0; t < KT; ++t) {
                float4 f0 = *(const float4*)(ap + t * 32);
                float4 f1 = *(const float4*)(ap + t * 32 + 4);
                bf16x8 o;
                o[0] = (short)f2bf(f0.x); o[1] = (short)f2bf(f0.y);
                o[2] = (short)f2bf(f0.z); o[3] = (short)f2bf(f0.w);
                o[4] = (short)f2bf(f1.x); o[5] = (short)f2bf(f1.y);
                o[6] = (short)f2bf(f1.z); o[7] = (short)f2bf(f1.w);
                afr[s][t] = o;
            }
        }
    }
    if (WRITEA && wave == 0) {
        #pragma unroll
        for (int s = 0; s < 2; ++s) {
            int ar = s ? ar1 : ar0;
            #pragma unroll
            for (int t = 0; t < KT; ++t)
                *(bf16x8*)(abf + (size_t)ar * K + t * 32 + lq * 8) = afr[s][t];
        }
    }

    const ushort* extb = (const ushort*)extra;
    float cs[2] = {0.f, 0.f}, cq[2] = {0.f, 0.f};

    #pragma unroll 1
    for (int cp = 0; cp < MW / 32; ++cp) {
        const int cbase = c0w + cp * 32;
        f32x4 acc[2][2] = {};
        const ushort* wp0 = W + (size_t)(cbase + lr) * K + lq * 8;
        const ushort* wp1 = wp0 + (size_t)16 * K;
        #pragma unroll
        for (int t = 0; t < KT; ++t) {
            bf16x8 b0 = *(const bf16x8*)(wp0 + t * 32);
            bf16x8 b1 = *(const bf16x8*)(wp1 + t * 32);
            acc[0][0] = __builtin_amdgcn_mfma_f32_16x16x32_bf16(afr[0][t], b0, acc[0][0], 0, 0, 0);
            acc[1][0] = __builtin_amdgcn_mfma_f32_16x16x32_bf16(afr[1][t], b0, acc[1][0], 0, 0, 0);
            acc[0][1] = __builtin_amdgcn_mfma_f32_16x16x32_bf16(afr[0][t], b1, acc[0][1], 0, 0, 0);
            acc[1][1] = __builtin_amdgcn_mfma_f32_16x16x32_bf16(afr[1][t], b1, acc[1][1], 0, 0, 0);
        }
        #pragma unroll
        for (int ct = 0; ct < 2; ++ct) {
            int col = cbase + ct * 16 + lr;
            float biasv = bias[col];
            #pragma unroll
            for (int s = 0; s < 2; ++s) {
                #pragma unroll
                for (int r = 0; r < 4; ++r) {
                    int grow = row0 + s * 16 + lq * 4 + r;
                    if (grow >= N) continue;
                    size_t o = (size_t)grow * M + col;
                    float v = acc[s][ct][r] + biasv;
                    if (EPI == 5) v += bf2f((short)extb[o]);
                    outb[o] = f2bf(v);
                    if (STATF) { cs[ct] += v; cq[ct] += v * v; }
                }
            }
        }
    }

    if (STATF) {
        #pragma unroll
        for (int ct = 0; ct < 2; ++ct) {
            float a = cs[ct], q = cq[ct];
            a += __shfl_xor(a, 16, 64); q += __shfl_xor(q, 16, 64);
            a += __shfl_xor(a, 32, 64); q += __shfl_xor(q, 32, 64);
            if (lq == 0) {
                int col = c0w + ct * 16 + lr;    // MW==32 when STATF
                unsafeAtomicAdd(&ostats[col], a);
                unsafeAtomicAdd(&ostats[128 + col], q);
            }
        }
        __threadfence();
        __syncthreads();
        __shared__ int isl;
        if (threadIdx.x == 0) isl = (atomicAdd(ticket, 1) == (int)gridDim.x - 1);
        __syncthreads();
        if (isl && threadIdx.x < 128) {
            __threadfence();
            int j = threadIdx.x;
            float sm = __hip_atomic_load(&ostats[j], __ATOMIC_RELAXED, __HIP_MEMORY_SCOPE_AGENT);
            float sq = __hip_atomic_load(&ostats[128 + j], __ATOMIC_RELAXED, __HIP_MEMORY_SCOPE_AGENT);
            float mean = sm / (float)N;
            float var  = sq / (float)N - mean * mean;
            float sc = g[j] * rsqrtf(var + 1e-5f);
            ostats[256 + j] = sc;
            ostats[384 + j] = bb[j] - mean * sc;
        }
    }
}

// ---------------------------------------------------------------------------
// Fused FFN: lin1 (BN1 on A-load, leaky) -> LDS hid tile -> lin2 (+bias +
// BN1(y1) residual) -> y2b, with BN2 stats fused into the epilogue.
// Phase 1 computes the TRANSPOSED product D[k_out][row] = w1 x^T so each lane
// holds 4 consecutive k_out -> one 8B LDS store into k-major hid[k8][row][8];
// phase 2 reads A-frags back as 16B b128 (2-way conflicts only = free).
// ---------------------------------------------------------------------------
__global__ __launch_bounds__(256)
void ffn_fused_kernel(const ushort* __restrict__ y1b,
                      const ushort* __restrict__ w1b, const float* __restrict__ lb1,
                      const ushort* __restrict__ w2b, const float* __restrict__ lb2,
                      const float* __restrict__ stats1,
                      float* __restrict__ stats2, int* __restrict__ ticket,
                      const float* __restrict__ g2, const float* __restrict__ b2,
                      ushort* __restrict__ y2b, int N)
{
    __shared__ ushort hid[64 * 32 * 8];   // [k8][row][8], 32 KB
    const int lane = threadIdx.x & 63, wave = threadIdx.x >> 6;
    const int lr = lane & 15, lq = lane >> 4;
    const int row0 = blockIdx.x * 32;
    int ar0 = min(row0 + lr, N - 1);
    int ar1 = min(row0 + 16 + lr, N - 1);

    // x-frags: BN1-transformed y1 rows (serve as B operand in phase 1,
    // identical register layout to A operand of x).
    bf16x8 xfr[2][4];
    #pragma unroll
    for (int s = 0; s < 2; ++s) {
        int ar = s ? ar1 : ar0;
        const ushort* ap = y1b + (size_t)ar * 128 + lq * 8;
        #pragma unroll
        for (int t = 0; t < 4; ++t) {
            bf16x8 raw = *(const bf16x8*)(ap + t * 32);
            int kb = t * 32 + lq * 8;
            const float4* scp = (const float4*)(stats1 + 256 + kb);
            const float4* shp = (const float4*)(stats1 + 384 + kb);
            float4 sA = scp[0], sB = scp[1], hA = shp[0], hB = shp[1];
            bf16x8 o;
            o[0] = (short)f2bf(fmaf(bf2f(raw[0]), sA.x, hA.x));
            o[1] = (short)f2bf(fmaf(bf2f(raw[1]), sA.y, hA.y));
            o[2] = (short)f2bf(fmaf(bf2f(raw[2]), sA.z, hA.z));
            o[3] = (short)f2bf(fmaf(bf2f(raw[3]), sA.w, hA.w));
            o[4] = (short)f2bf(fmaf(bf2f(raw[4]), sB.x, hB.x));
            o[5] = (short)f2bf(fmaf(bf2f(raw[5]), sB.y, hB.y));
            o[6] = (short)f2bf(fmaf(bf2f(raw[6]), sB.z, hB.z));
            o[7] = (short)f2bf(fmaf(bf2f(raw[7]), sB.w, hB.w));
            xfr[s][t] = o;
        }
    }

    // phase 1: wave w covers k_out in [w*128, (w+1)*128)
    #pragma unroll 1
    for (int kb16 = 0; kb16 < 8; ++kb16) {
        int kbase = wave * 128 + kb16 * 16;
        const ushort* wp = w1b + (size_t)(kbase + lr) * 128 + lq * 8;
        f32x4 a0 = {0.f,0.f,0.f,0.f}, a1 = {0.f,0.f,0.f,0.f};
        #pragma unroll
        for (int t = 0; t < 4; ++t) {
            bf16x8 wf = *(const bf16x8*)(wp + t * 32);
            a0 = __builtin_amdgcn_mfma_f32_16x16x32_bf16(wf, xfr[0][t], a0, 0, 0, 0);
            a1 = __builtin_amdgcn_mfma_f32_16x16x32_bf16(wf, xfr[1][t], a1, 0, 0, 0);
        }
        // lane holds k_out = kbase + lq*4 + r, row = s*16 + lr
        float4 bi = *(const float4*)(lb1 + kbase + lq * 4);
        int k0 = kbase + lq * 4;
        int base0 = ((k0 >> 3) * 32) * 8 + (k0 & 7);
        float v0, v1, v2, v3;
        ushort4 p;
        v0 = a0[0] + bi.x; v0 = v0 > 0.f ? v0 : 0.01f * v0;
        v1 = a0[1] + bi.y; v1 = v1 > 0.f ? v1 : 0.01f * v1;
        v2 = a0[2] + bi.z; v2 = v2 > 0.f ? v2 : 0.01f * v2;
        v3 = a0[3] + bi.w; v3 = v3 > 0.f ? v3 : 0.01f * v3;
        p.x = f2bf(v0); p.y = f2bf(v1); p.z = f2bf(v2); p.w = f2bf(v3);
        *(ushort4*)&hid[base0 + lr * 8] = p;
        v0 = a1[0] + bi.x; v0 = v0 > 0.f ? v0 : 0.01f * v0;
        v1 = a1[1] + bi.y; v1 = v1 > 0.f ? v1 : 0.01f * v1;
        v2 = a1[2] + bi.z; v2 = v2 > 0.f ? v2 : 0.01f * v2;
        v3 = a1[3] + bi.w; v3 = v3 > 0.f ? v3 : 0.01f * v3;
        p.x = f2bf(v0); p.y = f2bf(v1); p.z = f2bf(v2); p.w = f2bf(v3);
        *(ushort4*)&hid[base0 + (16 + lr) * 8] = p;
    }
    __syncthreads();

    // phase 2: lin2, wave w covers out cols [w*32, w*32+32)
    int cb = wave * 32;
    f32x4 acc[2][2] = {};
    const ushort* q0 = w2b + (size_t)(cb + lr) * 512 + lq * 8;
    const ushort* q1 = q0 + (size_t)16 * 512;
    #pragma unroll
    for (int t = 0; t < 16; ++t) {
        bf16x8 h0 = *(const bf16x8*)&hid[((t * 4 + lq) * 32 + lr) * 8];
        bf16x8 h1 = *(const bf16x8*)&hid[((t * 4 + lq) * 32 + 16 + lr) * 8];
        bf16x8 b0 = *(const bf16x8*)(q0 + t * 32);
        bf16x8 b1 = *(const bf16x8*)(q1 + t * 32);
        acc[0][0] = __builtin_amdgcn_mfma_f32_16x16x32_bf16(h0, b0, acc[0][0], 0, 0, 0);
        acc[1][0] = __builtin_amdgcn_mfma_f32_16x16x32_bf16(h1, b0, acc[1][0], 0, 0, 0);
        acc[0][1] = __builtin_amdgcn_mfma_f32_16x16x32_bf16(h0, b1, acc[0][1], 0, 0, 0);
        acc[1][1] = __builtin_amdgcn_mfma_f32_16x16x32_bf16(h1, b1, acc[1][1], 0, 0, 0);
    }

    float cs[2] = {0.f, 0.f}, cq[2] = {0.f, 0.f};
    #pragma unroll
    for (int ct = 0; ct < 2; ++ct) {
        int col = cb + ct * 16 + lr;
        float biasv = lb2[col];
        float scv = stats1[256 + col], shv = stats1[384 + col];
        #pragma unroll
        for (int s = 0; s < 2; ++s) {
            #pragma unroll
            for (int r = 0; r < 4; ++r) {
                int grow = row0 + s * 16 + lq * 4 + r;
                if (grow >= N) continue;
                size_t o = (size_t)grow * 128 + col;
                float v = acc[s][ct][r] + biasv + fmaf(bf2f((short)y1b[o]), scv, shv);
                y2b[o] = f2bf(v);
                cs[ct] += v; cq[ct] += v * v;
            }
        }
    }
    #pragma unroll
    for (int ct = 0; ct < 2; ++ct) {
        float a = cs[ct], q = cq[ct];
        a += __shfl_xor(a, 16, 64); q += __shfl_xor(q, 16, 64);
        a += __shfl_xor(a, 32, 64); q += __shfl_xor(q, 32, 64);
        if (lq == 0) {
            int col = cb + ct * 16 + lr;
            unsafeAtomicAdd(&stats2[col], a);
            unsafeAtomicAdd(&stats2[128 + col], q);
        }
    }
    __threadfence();
    __syncthreads();
    __shared__ int isl;
    if (threadIdx.x == 0) isl = (atomicAdd(ticket, 1) == (int)gridDim.x - 1);
    __syncthreads();
    if (isl && threadIdx.x < 128) {
        __threadfence();
        int j = threadIdx.x;
        float sm = __hip_atomic_load(&stats2[j], __ATOMIC_RELAXED, __HIP_MEMORY_SCOPE_AGENT);
        float sq = __hip_atomic_load(&stats2[128 + j], __ATOMIC_RELAXED, __HIP_MEMORY_SCOPE_AGENT);
        float mean = sm / (float)N;
        float var  = sq / (float)N - mean * mean;
        float sc = g2[j] * rsqrtf(var + 1e-5f);
        stats2[256 + j] = sc;
        stats2[384 + j] = b2[j] - mean * sc;
    }
}

// ---------------------------------------------------------------------------
// Weights -> bf16; QKV fused [384x128] with q-scaling folded.
// ---------------------------------------------------------------------------
__global__ __launch_bounds__(256)
void convert_weights_kernel(const float* __restrict__ qw, const float* __restrict__ qb,
                            const float* __restrict__ kw, const float* __restrict__ vw,
                            const float* __restrict__ ow, const float* __restrict__ w1,
                            const float* __restrict__ w2,
                            ushort* __restrict__ wqkv, ushort* __restrict__ wout,
                            ushort* __restrict__ w1b, ushort* __restrict__ w2b,
                            float* __restrict__ bqkv)
{
    int i = blockIdx.x * 256 + threadIdx.x;
    if (i < 49152) {
        int row = i >> 7;
        float v;
        if (row < 128)      v = 0.25f * qw[i];
        else if (row < 256) v = kw[i - 16384];
        else                v = vw[i - 32768];
        wqkv[i] = f2bf(v);
        return;
    }
    int j = i - 49152;
    if (j < 16384) { wout[j] = f2bf(ow[j]); return; }
    j -= 16384;
    if (j < 65536) { w1b[j] = f2bf(w1[j]); return; }
    j -= 65536;
    if (j < 65536) { w2b[j] = f2bf(w2[j]); return; }
    j -= 65536;
    if (j < 384) bqkv[j] = (j < 128) ? 0.25f * qb[j] : 0.f;
}

// ---------------------------------------------------------------------------
// CSR build: counting sort of edges by destination.
// ---------------------------------------------------------------------------
__global__ __launch_bounds__(256)
void deg_count_kernel(const int* __restrict__ ei, long long E0, int* __restrict__ deg)
{
    long long e = (long long)blockIdx.x * 256 + threadIdx.x;
    if (e < E0) atomicAdd(&deg[ei[E0 + e]], 1);
}

__global__ __launch_bounds__(256)
void scan_block_sum(const int* __restrict__ deg, int n, int* __restrict__ bsum)
{
    __shared__ int sh[256];
    int i = blockIdx.x * 256 + threadIdx.x;
    sh[threadIdx.x] = (i < n) ? deg[i] : 0;
    __syncthreads();
    for (int ofs = 128; ofs > 0; ofs >>= 1) {
        if (threadIdx.x < ofs) sh[threadIdx.x] += sh[threadIdx.x + ofs];
        __syncthreads();
    }
    if (threadIdx.x == 0) bsum[blockIdx.x] = sh[0];
}

// fused: per-block offset from inline scan of bsum (nb <= 256), then local scan
__global__ __launch_bounds__(256)
void scan_final(const int* __restrict__ deg, int n, const int* __restrict__ bsum,
                int nb, int* __restrict__ rowptr)
{
    __shared__ int sb[256];
    __shared__ int sh[256];
    int t = threadIdx.x;
    sb[t] = (t < nb) ? bsum[t] : 0;
    __syncthreads();
    for (int ofs = 1; ofs < 256; ofs <<= 1) {
        int v = (t >= ofs) ? sb[t - ofs] : 0;
        __syncthreads();
        sb[t] += v;
        __syncthreads();
    }
    int boff = (blockIdx.x == 0) ? 0 : sb[blockIdx.x - 1];

    int i = blockIdx.x * 256 + t;
    int v = (i < n) ? deg[i] : 0;
    sh[t] = v;
    __syncthreads();
    for (int ofs = 1; ofs < 256; ofs <<= 1) {
        int u = (t >= ofs) ? sh[t - ofs] : 0;
        __syncthreads();
        sh[t] += u;
        __syncthreads();
    }
    if (i < n) rowptr[i] = boff + sh[t] - v;
    if (i == n - 1) rowptr[n] = boff + sh[t];
}

__global__ __launch_bounds__(256)
void scatter_kernel(const int* __restrict__ ei, long long E0,
                    const int* __restrict__ rowptr, int* __restrict__ cnt,
                    int* __restrict__ col)
{
    long long e = (long long)blockIdx.x * 256 + threadIdx.x;
    if (e >= E0) return;
    int s = ei[e], d = ei[E0 + e];
    int pos = rowptr[d] + atomicAdd(&cnt[d], 1);
    col[pos] = s;
}

// ---------------------------------------------------------------------------
// Fused gather attention, WAVE-PER-NODE: 64 lanes = 8 heads x 8 edge slots.
// No divergence (all lanes walk the same node), 8x finer balance, 50k waves.
// qkv row = 48 uint4: q at h*2, k at 16+h*2, v at 32+h*2. idx 0 = self loop.
// ---------------------------------------------------------------------------
__global__ __launch_bounds__(256)
void gat_agg_kernel(const int* __restrict__ rowptr, const int* __restrict__ col,
                    const ushort* __restrict__ qkv, ushort* __restrict__ agg, int N)
{
    int node = blockIdx.x * 4 + (threadIdx.x >> 6);
    if (node >= N) return;
    int lane = threadIdx.x & 63;
    int es = lane >> 3, h = lane & 7;
    const uint4* Q = (const uint4*)qkv;

    const uint4* qp = Q + (size_t)node * 48 + h * 2;
    uint4 qa = qp[0], qb = qp[1];
    float qf[16];
    qf[0]=bflo(qa.x); qf[1]=bfhi(qa.x); qf[2]=bflo(qa.y); qf[3]=bfhi(qa.y);
    qf[4]=bflo(qa.z); qf[5]=bfhi(qa.z); qf[6]=bflo(qa.w); qf[7]=bfhi(qa.w);
    qf[8]=bflo(qb.x); qf[9]=bfhi(qb.x); qf[10]=bflo(qb.y); qf[11]=bfhi(qb.y);
    qf[12]=bflo(qb.z); qf[13]=bfhi(qb.z); qf[14]=bflo(qb.w); qf[15]=bfhi(qb.w);

    float num[16];
    #pragma unroll
    for (int i = 0; i < 16; i++) num[i] = 0.f;
    float den = 0.f;

    int beg = rowptr[node];
    int total = rowptr[node + 1] - beg + 1;   // + self loop at idx 0
    for (int idx = es; idx < total; idx += 8) {
        int s = (idx == 0) ? node : col[beg + idx - 1];
        const uint4* rp = Q + (size_t)s * 48 + h * 2;
        uint4 ka = rp[16], kb = rp[17], va = rp[32], vb = rp[33];
        float ev = __expf(dot16(qf, ka, kb));
        den += ev;
        acc16(num, ev, va, vb);
    }

    #pragma unroll
    for (int m = 8; m < 64; m <<= 1) {
        den += __shfl_xor(den, m, 64);
        #pragma unroll
        for (int i = 0; i < 16; i++) num[i] += __shfl_xor(num[i], m, 64);
    }

    if (es == 0) {
        float inv = 1.f / (den + 1e-16f);
        uint4 o0, o1;
        o0.x = (uint)f2bf(num[0]*inv)  | ((uint)f2bf(num[1]*inv)  << 16);
        o0.y = (uint)f2bf(num[2]*inv)  | ((uint)f2bf(num[3]*inv)  << 16);
        o0.z = (uint)f2bf(num[4]*inv)  | ((uint)f2bf(num[5]*inv)  << 16);
        o0.w = (uint)f2bf(num[6]*inv)  | ((uint)f2bf(num[7]*inv)  << 16);
        o1.x = (uint)f2bf(num[8]*inv)  | ((uint)f2bf(num[9]*inv)  << 16);
        o1.y = (uint)f2bf(num[10]*inv) | ((uint)f2bf(num[11]*inv) << 16);
        o1.z = (uint)f2bf(num[12]*inv) | ((uint)f2bf(num[13]*inv) << 16);
        o1.w = (uint)f2bf(num[14]*inv) | ((uint)f2bf(num[15]*inv) << 16);
        uint4* op = (uint4*)(agg + (size_t)node * 128 + h * 16);
        op[0] = o0; op[1] = o1;
    }
}

// final BN apply: bf16 in -> fp32 out
__global__ __launch_bounds__(256)
void bn_apply_out_kernel(const ushort* __restrict__ y, const float* __restrict__ stats,
                         float* __restrict__ out, int total4)
{
    int i = blockIdx.x * 256 + threadIdx.x;
    if (i >= total4) return;
    uint2 u = reinterpret_cast<const uint2*>(y)[i];
    int j = (i * 4) & (D - 1);
    float4 v;
    v.x = bflo(u.x) * stats[256 + j + 0] + stats[384 + j + 0];
    v.y = bfhi(u.x) * stats[256 + j + 1] + stats[384 + j + 1];
    v.z = bflo(u.y) * stats[256 + j + 2] + stats[384 + j + 2];
    v.w = bfhi(u.y) * stats[256 + j + 3] + stats[384 + j + 3];
    reinterpret_cast<float4*>(out)[i] = v;
}

// ---------------------------------------------------------------------------
extern "C" void kernel_launch(void* const* d_in, const int* in_sizes, int n_in,
                              void* d_out, int out_size, void* d_ws, size_t ws_size,
                              hipStream_t stream)
{
    const float* src    = (const float*)d_in[0];
    const int*   ei     = (const int*)  d_in[1];
    const float* q_w    = (const float*)d_in[2];
    const float* q_b    = (const float*)d_in[3];
    const float* k_w    = (const float*)d_in[4];
    const float* v_w    = (const float*)d_in[5];
    const float* out_w  = (const float*)d_in[6];
    const float* out_b  = (const float*)d_in[7];
    const float* g1     = (const float*)d_in[8];
    const float* b1     = (const float*)d_in[9];
    const float* lin1_w = (const float*)d_in[10];
    const float* lin1_b = (const float*)d_in[11];
    const float* lin2_w = (const float*)d_in[12];
    const float* lin2_b = (const float*)d_in[13];
    const float* g2     = (const float*)d_in[14];
    const float* b2     = (const float*)d_in[15];

    const int N        = in_sizes[0] / D;        // 50000
    const long long E0 = in_sizes[1] / 2;        // 800000

    // ---- workspace layout (float units) ----
    float* ws = (float*)d_ws;
    size_t off = 0;
    ushort* qkv   = (ushort*)(ws + off); off += (size_t)N * 192;   // N*384 bf16
    ushort* agg   = (ushort*)(ws + off); off += (size_t)N * 64;
    ushort* srcbf = (ushort*)(ws + off); off += (size_t)N * 64;
    ushort* y1b   = (ushort*)(ws + off); off += (size_t)N * 64;
    ushort* y2b   = (ushort*)(ws + off); off += (size_t)N * 64;
    ushort* wqkv  = (ushort*)(ws + off); off += 24576;             // 384*128
    ushort* woutb = (ushort*)(ws + off); off += 8192;              // 128*128
    ushort* w1b   = (ushort*)(ws + off); off += 32768;             // 512*128
    ushort* w2b   = (ushort*)(ws + off); off += 32768;             // 128*512
    float*  bqkv  = ws + off;            off += 384;
    size_t zero_start = off;
    int* deg    = (int*)(ws + off); off += N;
    int* cnt    = (int*)(ws + off); off += N;
    float* stats1 = ws + off; off += 512;
    float* stats2 = ws + off; off += 512;
    int* tickets  = (int*)(ws + off); off += 2;
    size_t zero_cnt = off - zero_start;
    int* rowptr = (int*)(ws + off); off += N + 1;
    int* bsum   = (int*)(ws + off); off += 256;
    int* col    = (int*)(ws + off); off += E0;

    hipMemsetAsync(ws + zero_start, 0, zero_cnt * sizeof(float), stream);

    dim3 blk(256);

    // ---- weight conversion ----
    int cw_total = 49152 + 16384 + 65536 + 65536 + 384;
    hipLaunchKernelGGL(convert_weights_kernel, dim3((cw_total + 255) / 256), blk, 0, stream,
                       q_w, q_b, k_w, v_w, out_w, lin1_w, lin2_w,
                       wqkv, woutb, w1b, w2b, bqkv);

    // ---- CSR build ----
    dim3 gE0((unsigned)((E0 + 255) / 256));
    hipLaunchKernelGGL(deg_count_kernel, gE0, blk, 0, stream, ei, E0, deg);
    int nb = (N + 255) / 256;   // 196
    hipLaunchKernelGGL(scan_block_sum, dim3(nb), blk, 0, stream, deg, N, bsum);
    hipLaunchKernelGGL(scan_final, dim3(nb), blk, 0, stream, deg, N, bsum, nb, rowptr);
    hipLaunchKernelGGL(scatter_kernel, gE0, blk, 0, stream, ei, E0, rowptr, cnt, col);

    dim3 gG((N + 31) / 32);   // 1563 blocks

    // ---- fused QKV projection (fp32 A converted on load; emits srcbf) ----
    hipLaunchKernelGGL((gemm_v2_kernel<1, 0, 128, 96, true, false>), gG, blk, 0, stream,
                       src, wqkv, bqkv, nullptr, qkv, srcbf,
                       nullptr, nullptr, nullptr, nullptr, N);

    // ---- fused softmax + aggregation (wave per node) ----
    hipLaunchKernelGGL(gat_agg_kernel, dim3((N + 3) / 4), blk, 0, stream,
                       rowptr, col, qkv, agg, N);

    // ---- out-projection + bias + bf16 src residual -> y1b; BN1 stats fused ----
    hipLaunchKernelGGL((gemm_v2_kernel<0, 5, 128, 32, false, true>), gG, blk, 0, stream,
                       agg, woutb, out_b, srcbf, y1b, nullptr,
                       stats1, &tickets[0], g1, b1, N);

    // ---- fused FFN (lin1 + leaky -> LDS -> lin2 + BN1 residual); BN2 stats fused ----
    hipLaunchKernelGGL(ffn_fused_kernel, gG, blk, 0, stream,
                       y1b, w1b, lin1_b, w2b, lin2_b, stats1,
                       stats2, &tickets[1], g2, b2, y2b, N);

    // ---- BN2 apply -> d_out fp32 ----
    int total4 = N * D / 4;
    hipLaunchKernelGGL(bn_apply_out_kernel, dim3((total4 + 255) / 256), blk, 0, stream,
                       y2b, stats2, (float*)d_out, total4);
}

// Round 7
// 470.005 us; speedup vs baseline: 1.4333x; 1.4333x over previous
//
#include <hip/hip_runtime.h>
#include <math.h>

#define D 128
#define H 8
#define HD 16

typedef __attribute__((ext_vector_type(8))) short bf16x8;
typedef __attribute__((ext_vector_type(4))) float f32x4;

__device__ __forceinline__ ushort f2bf(float x) {
    union { float f; unsigned u; } v; v.f = x;
    unsigned r = v.u + 0x7fffu + ((v.u >> 16) & 1u);   // RNE
    return (ushort)(r >> 16);
}
__device__ __forceinline__ float bflo(unsigned u) {
    union { unsigned u; float f; } x; x.u = u << 16; return x.f;
}
__device__ __forceinline__ float bfhi(unsigned u) {
    union { unsigned u; float f; } x; x.u = u & 0xffff0000u; return x.f;
}
__device__ __forceinline__ float bf2f(short s) {
    union { unsigned u; float f; } x; x.u = ((unsigned)(ushort)s) << 16; return x.f;
}

__device__ __forceinline__ float dot16(const float* qf, uint4 a, uint4 b) {
    float w;
    w  = qf[0]  * bflo(a.x) + qf[1]  * bfhi(a.x);
    w += qf[2]  * bflo(a.y) + qf[3]  * bfhi(a.y);
    w += qf[4]  * bflo(a.z) + qf[5]  * bfhi(a.z);
    w += qf[6]  * bflo(a.w) + qf[7]  * bfhi(a.w);
    w += qf[8]  * bflo(b.x) + qf[9]  * bfhi(b.x);
    w += qf[10] * bflo(b.y) + qf[11] * bfhi(b.y);
    w += qf[12] * bflo(b.z) + qf[13] * bfhi(b.z);
    w += qf[14] * bflo(b.w) + qf[15] * bfhi(b.w);
    return w;
}
__device__ __forceinline__ void acc16(float* num, float e, uint4 a, uint4 b) {
    num[0]  = fmaf(e, bflo(a.x), num[0]);  num[1]  = fmaf(e, bfhi(a.x), num[1]);
    num[2]  = fmaf(e, bflo(a.y), num[2]);  num[3]  = fmaf(e, bfhi(a.y), num[3]);
    num[4]  = fmaf(e, bflo(a.z), num[4]);  num[5]  = fmaf(e, bfhi(a.z), num[5]);
    num[6]  = fmaf(e, bflo(a.w), num[6]);  num[7]  = fmaf(e, bfhi(a.w), num[7]);
    num[8]  = fmaf(e, bflo(b.x), num[8]);  num[9]  = fmaf(e, bfhi(b.x), num[9]);
    num[10] = fmaf(e, bflo(b.y), num[10]); num[11] = fmaf(e, bfhi(b.y), num[11]);
    num[12] = fmaf(e, bflo(b.z), num[12]); num[13] = fmaf(e, bfhi(b.z), num[13]);
    num[14] = fmaf(e, bflo(b.w), num[14]); num[15] = fmaf(e, bfhi(b.w), num[15]);
}

// ---------------------------------------------------------------------------
// bf16 MFMA GEMM (R5-proven). Block = 4 waves, 32 rows; wave w handles cols
// [w*MW,(w+1)*MW). Two A-strips/wave so every B-load feeds 2 MFMAs. K chunked
// at 128 to bound VGPRs. No LDS, no barriers, no fences.
// AMODE: 0 = A bf16; 1 = A fp32 (convert on load); 2 = A bf16 + BN(stats).
// EPI:   0 = bias; 2 = bias+leakyrelu; 3 = bias + fp32 residual (extra);
//        4 = bias + BN1-transformed bf16 residual (extra). Output bf16.
// ---------------------------------------------------------------------------
template<int AMODE, int EPI, int K, int MW>
__global__ __launch_bounds__(256)
void gemm_v2_kernel(const void* __restrict__ Ap,
                    const ushort* __restrict__ W,
                    const float* __restrict__ bias,
                    const void* __restrict__ extra,
                    const float* __restrict__ stats,
                    ushort* __restrict__ outb,
                    int N)
{
    constexpr int M   = MW * 4;
    constexpr int KC  = (K < 128) ? K : 128;
    constexpr int KT  = KC / 32;
    constexpr int NKC = K / KC;

    const int lane = threadIdx.x & 63, wave = threadIdx.x >> 6;
    const int lr = lane & 15, lq = lane >> 4;
    const int row0 = blockIdx.x * 32;
    const int c0w  = wave * MW;

    int ar0 = min(row0 + lr, N - 1);
    int ar1 = min(row0 + 16 + lr, N - 1);

    bf16x8 afr[2][KT];

    auto loadA = [&](int kc) {
        #pragma unroll
        for (int s = 0; s < 2; ++s) {
            int ar = s ? ar1 : ar0;
            if (AMODE == 0 || AMODE == 2) {
                const ushort* ap = (const ushort*)Ap + (size_t)ar * K + kc * KC + lq * 8;
                #pragma unroll
                for (int t = 0; t < KT; ++t) {
                    bf16x8 raw = *(const bf16x8*)(ap + t * 32);
                    if (AMODE == 0) {
                        afr[s][t] = raw;
                    } else {
                        int kb = kc * KC + t * 32 + lq * 8;
                        const float4* scp = (const float4*)(stats + 256 + kb);
                        const float4* shp = (const float4*)(stats + 384 + kb);
                        float4 sA = scp[0], sB = scp[1], hA = shp[0], hB = shp[1];
                        bf16x8 o;
                        o[0] = (short)f2bf(fmaf(bf2f(raw[0]), sA.x, hA.x));
                        o[1] = (short)f2bf(fmaf(bf2f(raw[1]), sA.y, hA.y));
                        o[2] = (short)f2bf(fmaf(bf2f(raw[2]), sA.z, hA.z));
                        o[3] = (short)f2bf(fmaf(bf2f(raw[3]), sA.w, hA.w));
                        o[4] = (short)f2bf(fmaf(bf2f(raw[4]), sB.x, hB.x));
                        o[5] = (short)f2bf(fmaf(bf2f(raw[5]), sB.y, hB.y));
                        o[6] = (short)f2bf(fmaf(bf2f(raw[6]), sB.z, hB.z));
                        o[7] = (short)f2bf(fmaf(bf2f(raw[7]), sB.w, hB.w));
                        afr[s][t] = o;
                    }
                }
            } else {
                const float* ap = (const float*)Ap + (size_t)ar * K + kc * KC + lq * 8;
                #pragma unroll
                for (int t = 0; t < KT; ++t) {
                    float4 f0 = *(const float4*)(ap + t * 32);
                    float4 f1 = *(const float4*)(ap + t * 32 + 4);
                    bf16x8 o;
                    o[0] = (short)f2bf(f0.x); o[1] = (short)f2bf(f0.y);
                    o[2] = (short)f2bf(f0.z); o[3] = (short)f2bf(f0.w);
                    o[4] = (short)f2bf(f1.x); o[5] = (short)f2bf(f1.y);
                    o[6] = (short)f2bf(f1.z); o[7] = (short)f2bf(f1.w);
                    afr[s][t] = o;
                }
            }
        }
    };

    if (NKC == 1) loadA(0);

    const float*  extf = (const float*)extra;
    const ushort* extb = (const ushort*)extra;

    #pragma unroll 1
    for (int cp = 0; cp < MW / 32; ++cp) {
        const int cbase = c0w + cp * 32;
        f32x4 acc[2][2] = {};

        #pragma unroll 1
        for (int kc = 0; kc < NKC; ++kc) {
            if (NKC > 1) loadA(kc);
            const ushort* wp0 = W + (size_t)(cbase + lr) * K + kc * KC + lq * 8;
            const ushort* wp1 = wp0 + (size_t)16 * K;
            #pragma unroll
            for (int t = 0; t < KT; ++t) {
                bf16x8 b0 = *(const bf16x8*)(wp0 + t * 32);
                bf16x8 b1 = *(const bf16x8*)(wp1 + t * 32);
                acc[0][0] = __builtin_amdgcn_mfma_f32_16x16x32_bf16(afr[0][t], b0, acc[0][0], 0, 0, 0);
                acc[1][0] = __builtin_amdgcn_mfma_f32_16x16x32_bf16(afr[1][t], b0, acc[1][0], 0, 0, 0);
                acc[0][1] = __builtin_amdgcn_mfma_f32_16x16x32_bf16(afr[0][t], b1, acc[0][1], 0, 0, 0);
                acc[1][1] = __builtin_amdgcn_mfma_f32_16x16x32_bf16(afr[1][t], b1, acc[1][1], 0, 0, 0);
            }
        }

        #pragma unroll
        for (int ct = 0; ct < 2; ++ct) {
            int col = cbase + ct * 16 + lr;
            float biasv = bias[col];
            float scv = 0.f, shv = 0.f;
            if (EPI == 4) { scv = stats[256 + col]; shv = stats[384 + col]; }
            #pragma unroll
            for (int s = 0; s < 2; ++s) {
                #pragma unroll
                for (int r = 0; r < 4; ++r) {
                    int grow = row0 + s * 16 + lq * 4 + r;
                    if (grow >= N) continue;
                    size_t o = (size_t)grow * M + col;
                    float v = acc[s][ct][r] + biasv;
                    if (EPI == 2) {
                        v = v > 0.f ? v : 0.01f * v;
                    } else if (EPI == 3) {
                        v += extf[o];
                    } else if (EPI == 4) {
                        v += fmaf(bf2f((short)extb[o]), scv, shv);
                    }
                    outb[o] = f2bf(v);
                }
            }
        }
    }
}

// ---------------------------------------------------------------------------
// Weights -> bf16; QKV fused [384x128] with q-scaling folded.
// ---------------------------------------------------------------------------
__global__ __launch_bounds__(256)
void convert_weights_kernel(const float* __restrict__ qw, const float* __restrict__ qb,
                            const float* __restrict__ kw, const float* __restrict__ vw,
                            const float* __restrict__ ow, const float* __restrict__ w1,
                            const float* __restrict__ w2,
                            ushort* __restrict__ wqkv, ushort* __restrict__ wout,
                            ushort* __restrict__ w1b, ushort* __restrict__ w2b,
                            float* __restrict__ bqkv)
{
    int i = blockIdx.x * 256 + threadIdx.x;
    if (i < 49152) {
        int row = i >> 7;
        float v;
        if (row < 128)      v = 0.25f * qw[i];
        else if (row < 256) v = kw[i - 16384];
        else                v = vw[i - 32768];
        wqkv[i] = f2bf(v);
        return;
    }
    int j = i - 49152;
    if (j < 16384) { wout[j] = f2bf(ow[j]); return; }
    j -= 16384;
    if (j < 65536) { w1b[j] = f2bf(w1[j]); return; }
    j -= 65536;
    if (j < 65536) { w2b[j] = f2bf(w2[j]); return; }
    j -= 65536;
    if (j < 384) bqkv[j] = (j < 128) ? 0.25f * qb[j] : 0.f;
}

// ---------------------------------------------------------------------------
// CSR build: counting sort of edges by destination.
// ---------------------------------------------------------------------------
__global__ __launch_bounds__(256)
void deg_count_kernel(const int* __restrict__ ei, long long E0, int* __restrict__ deg)
{
    long long e = (long long)blockIdx.x * 256 + threadIdx.x;
    if (e < E0) atomicAdd(&deg[ei[E0 + e]], 1);
}

__global__ __launch_bounds__(256)
void scan_block_sum(const int* __restrict__ deg, int n, int* __restrict__ bsum)
{
    __shared__ int sh[256];
    int i = blockIdx.x * 256 + threadIdx.x;
    sh[threadIdx.x] = (i < n) ? deg[i] : 0;
    __syncthreads();
    for (int ofs = 128; ofs > 0; ofs >>= 1) {
        if (threadIdx.x < ofs) sh[threadIdx.x] += sh[threadIdx.x + ofs];
        __syncthreads();
    }
    if (threadIdx.x == 0) bsum[blockIdx.x] = sh[0];
}

// fused: per-block offset from inline scan of bsum (nb <= 256), then local scan
__global__ __launch_bounds__(256)
void scan_final(const int* __restrict__ deg, int n, const int* __restrict__ bsum,
                int nb, int* __restrict__ rowptr)
{
    __shared__ int sb[256];
    __shared__ int sh[256];
    int t = threadIdx.x;
    sb[t] = (t < nb) ? bsum[t] : 0;
    __syncthreads();
    for (int ofs = 1; ofs < 256; ofs <<= 1) {
        int v = (t >= ofs) ? sb[t - ofs] : 0;
        __syncthreads();
        sb[t] += v;
        __syncthreads();
    }
    int boff = (blockIdx.x == 0) ? 0 : sb[blockIdx.x - 1];

    int i = blockIdx.x * 256 + t;
    int v = (i < n) ? deg[i] : 0;
    sh[t] = v;
    __syncthreads();
    for (int ofs = 1; ofs < 256; ofs <<= 1) {
        int u = (t >= ofs) ? sh[t - ofs] : 0;
        __syncthreads();
        sh[t] += u;
        __syncthreads();
    }
    if (i < n) rowptr[i] = boff + sh[t] - v;
    if (i == n - 1) rowptr[n] = boff + sh[t];
}

__global__ __launch_bounds__(256)
void scatter_kernel(const int* __restrict__ ei, long long E0,
                    const int* __restrict__ rowptr, int* __restrict__ cnt,
                    int* __restrict__ col)
{
    long long e = (long long)blockIdx.x * 256 + threadIdx.x;
    if (e >= E0) return;
    int s = ei[e], d = ei[E0 + e];
    int pos = rowptr[d] + atomicAdd(&cnt[d], 1);
    col[pos] = s;
}

// ---------------------------------------------------------------------------
// Fused gather attention, WAVE-PER-NODE: 64 lanes = 8 heads x 8 edge slots,
// butterfly reduce over edge slots at the end. Zero divergence, 8x finer
// load balance than thread-per-(node,head), 50k waves.
// qkv row = 48 uint4: q at h*2, k at 16+h*2, v at 32+h*2. idx 0 = self loop.
// ---------------------------------------------------------------------------
__global__ __launch_bounds__(256)
void gat_agg_kernel(const int* __restrict__ rowptr, const int* __restrict__ col,
                    const ushort* __restrict__ qkv, ushort* __restrict__ agg, int N)
{
    int node = blockIdx.x * 4 + (threadIdx.x >> 6);
    if (node >= N) return;
    int lane = threadIdx.x & 63;
    int es = lane >> 3, h = lane & 7;
    const uint4* Q = (const uint4*)qkv;

    const uint4* qp = Q + (size_t)node * 48 + h * 2;
    uint4 qa = qp[0], qb = qp[1];
    float qf[16];
    qf[0]=bflo(qa.x); qf[1]=bfhi(qa.x); qf[2]=bflo(qa.y); qf[3]=bfhi(qa.y);
    qf[4]=bflo(qa.z); qf[5]=bfhi(qa.z); qf[6]=bflo(qa.w); qf[7]=bfhi(qa.w);
    qf[8]=bflo(qb.x); qf[9]=bfhi(qb.x); qf[10]=bflo(qb.y); qf[11]=bfhi(qb.y);
    qf[12]=bflo(qb.z); qf[13]=bfhi(qb.z); qf[14]=bflo(qb.w); qf[15]=bfhi(qb.w);

    float num[16];
    #pragma unroll
    for (int i = 0; i < 16; i++) num[i] = 0.f;
    float den = 0.f;

    int beg = rowptr[node];
    int total = rowptr[node + 1] - beg + 1;   // + self loop at idx 0
    for (int idx = es; idx < total; idx += 8) {
        int s = (idx == 0) ? node : col[beg + idx - 1];
        const uint4* rp = Q + (size_t)s * 48 + h * 2;
        uint4 ka = rp[16], kb = rp[17], va = rp[32], vb = rp[33];
        float ev = __expf(dot16(qf, ka, kb));
        den += ev;
        acc16(num, ev, va, vb);
    }

    #pragma unroll
    for (int m = 8; m < 64; m <<= 1) {
        den += __shfl_xor(den, m, 64);
        #pragma unroll
        for (int i = 0; i < 16; i++) num[i] += __shfl_xor(num[i], m, 64);
    }

    if (es == 0) {
        float inv = 1.f / (den + 1e-16f);
        uint4 o0, o1;
        o0.x = (uint)f2bf(num[0]*inv)  | ((uint)f2bf(num[1]*inv)  << 16);
        o0.y = (uint)f2bf(num[2]*inv)  | ((uint)f2bf(num[3]*inv)  << 16);
        o0.z = (uint)f2bf(num[4]*inv)  | ((uint)f2bf(num[5]*inv)  << 16);
        o0.w = (uint)f2bf(num[6]*inv)  | ((uint)f2bf(num[7]*inv)  << 16);
        o1.x = (uint)f2bf(num[8]*inv)  | ((uint)f2bf(num[9]*inv)  << 16);
        o1.y = (uint)f2bf(num[10]*inv) | ((uint)f2bf(num[11]*inv) << 16);
        o1.z = (uint)f2bf(num[12]*inv) | ((uint)f2bf(num[13]*inv) << 16);
        o1.w = (uint)f2bf(num[14]*inv) | ((uint)f2bf(num[15]*inv) << 16);
        uint4* op = (uint4*)(agg + (size_t)node * 128 + h * 16);
        op[0] = o0; op[1] = o1;
    }
}

// ---------------------------------------------------------------------------
// BatchNorm stats over a bf16 [N x 128] tensor. Block covers 256 rows.
// ---------------------------------------------------------------------------
__global__ __launch_bounds__(256)
void bn_stats_bf16_kernel(const ushort* __restrict__ y, int N, float* __restrict__ stats)
{
    int jp = threadIdx.x & 63;     // feature pair
    int q4 = threadIdx.x >> 6;     // 0..3
    int r = blockIdx.x * 256 + q4;
    int rend = min(N, (int)(blockIdx.x + 1) * 256);
    float s0 = 0.f, qq0 = 0.f, s1 = 0.f, qq1 = 0.f;
    const uint* yp = (const uint*)y;
    for (; r < rend; r += 4) {
        uint u = yp[(size_t)r * 64 + jp];
        float a = bflo(u), b = bfhi(u);
        s0 += a; qq0 += a * a; s1 += b; qq1 += b * b;
    }
    __shared__ float sh[4][64][4];
    sh[q4][jp][0] = s0; sh[q4][jp][1] = qq0; sh[q4][jp][2] = s1; sh[q4][jp][3] = qq1;
    __syncthreads();
    if (threadIdx.x < 128) {
        int p = threadIdx.x >> 1;
        int w = threadIdx.x & 1;
        float ss = 0.f, sq = 0.f;
        #pragma unroll
        for (int i = 0; i < 4; i++) { ss += sh[i][p][w * 2]; sq += sh[i][p][w * 2 + 1]; }
        unsafeAtomicAdd(&stats[2 * p + w], ss);
        unsafeAtomicAdd(&stats[128 + 2 * p + w], sq);
    }
}

__global__ void bn_finalize_kernel(float* __restrict__ stats,
                                   const float* __restrict__ g,
                                   const float* __restrict__ b, int N)
{
    int j = threadIdx.x;  // 128 threads
    float mean = stats[j] / (float)N;
    float var  = stats[128 + j] / (float)N - mean * mean;
    float sc = g[j] * rsqrtf(var + 1e-5f);
    stats[256 + j] = sc;
    stats[384 + j] = b[j] - mean * sc;
}

// final BN apply: bf16 in -> fp32 out
__global__ __launch_bounds__(256)
void bn_apply_out_kernel(const ushort* __restrict__ y, const float* __restrict__ stats,
                         float* __restrict__ out, int total4)
{
    int i = blockIdx.x * 256 + threadIdx.x;
    if (i >= total4) return;
    uint2 u = reinterpret_cast<const uint2*>(y)[i];
    int j = (i * 4) & (D - 1);
    float4 v;
    v.x = bflo(u.x) * stats[256 + j + 0] + stats[384 + j + 0];
    v.y = bfhi(u.x) * stats[256 + j + 1] + stats[384 + j + 1];
    v.z = bflo(u.y) * stats[256 + j + 2] + stats[384 + j + 2];
    v.w = bfhi(u.y) * stats[256 + j + 3] + stats[384 + j + 3];
    reinterpret_cast<float4*>(out)[i] = v;
}

// ---------------------------------------------------------------------------
extern "C" void kernel_launch(void* const* d_in, const int* in_sizes, int n_in,
                              void* d_out, int out_size, void* d_ws, size_t ws_size,
                              hipStream_t stream)
{
    const float* src    = (const float*)d_in[0];
    const int*   ei     = (const int*)  d_in[1];
    const float* q_w    = (const float*)d_in[2];
    const float* q_b    = (const float*)d_in[3];
    const float* k_w    = (const float*)d_in[4];
    const float* v_w    = (const float*)d_in[5];
    const float* out_w  = (const float*)d_in[6];
    const float* out_b  = (const float*)d_in[7];
    const float* g1     = (const float*)d_in[8];
    const float* b1     = (const float*)d_in[9];
    const float* lin1_w = (const float*)d_in[10];
    const float* lin1_b = (const float*)d_in[11];
    const float* lin2_w = (const float*)d_in[12];
    const float* lin2_b = (const float*)d_in[13];
    const float* g2     = (const float*)d_in[14];
    const float* b2     = (const float*)d_in[15];

    const int N        = in_sizes[0] / D;        // 50000
    const long long E0 = in_sizes[1] / 2;        // 800000

    // ---- workspace layout (float units) ----
    float* ws = (float*)d_ws;
    size_t off = 0;
    ushort* qkv  = (ushort*)(ws + off); off += (size_t)N * 192;   // N*384 bf16
    ushort* agg  = (ushort*)(ws + off); off += (size_t)N * 64;    // N*128 bf16
    ushort* y1b  = (ushort*)(ws + off); off += (size_t)N * 64;
    ushort* hid  = (ushort*)(ws + off); off += (size_t)N * 256;   // N*512 bf16
    ushort* y2b  = (ushort*)(ws + off); off += (size_t)N * 64;
    ushort* wqkv = (ushort*)(ws + off); off += 24576;             // 384*128
    ushort* woutb= (ushort*)(ws + off); off += 8192;              // 128*128
    ushort* w1b  = (ushort*)(ws + off); off += 32768;             // 512*128
    ushort* w2b  = (ushort*)(ws + off); off += 32768;             // 128*512
    float*  bqkv = ws + off;            off += 384;
    size_t zero_start = off;
    int* deg    = (int*)(ws + off); off += N;
    int* cnt    = (int*)(ws + off); off += N;
    float* stats1 = ws + off; off += 512;
    float* stats2 = ws + off; off += 512;
    size_t zero_cnt = off - zero_start;
    int* rowptr = (int*)(ws + off); off += N + 1;
    int* bsum   = (int*)(ws + off); off += 256;
    int* col    = (int*)(ws + off); off += E0;

    hipMemsetAsync(ws + zero_start, 0, zero_cnt * sizeof(float), stream);

    dim3 blk(256);

    // ---- weight conversion ----
    int cw_total = 49152 + 16384 + 65536 + 65536 + 384;
    hipLaunchKernelGGL(convert_weights_kernel, dim3((cw_total + 255) / 256), blk, 0, stream,
                       q_w, q_b, k_w, v_w, out_w, lin1_w, lin2_w,
                       wqkv, woutb, w1b, w2b, bqkv);

    // ---- CSR build ----
    dim3 gE0((unsigned)((E0 + 255) / 256));
    hipLaunchKernelGGL(deg_count_kernel, gE0, blk, 0, stream, ei, E0, deg);
    int nb = (N + 255) / 256;   // 196
    hipLaunchKernelGGL(scan_block_sum, dim3(nb), blk, 0, stream, deg, N, bsum);
    hipLaunchKernelGGL(scan_final, dim3(nb), blk, 0, stream, deg, N, bsum, nb, rowptr);
    hipLaunchKernelGGL(scatter_kernel, gE0, blk, 0, stream, ei, E0, rowptr, cnt, col);

    dim3 gG((N + 31) / 32);   // 1563 blocks

    // ---- fused QKV projection (A = fp32 src, converted on load) ----
    hipLaunchKernelGGL((gemm_v2_kernel<1, 0, 128, 96>), gG, blk, 0, stream,
                       src, wqkv, bqkv, nullptr, nullptr, qkv, N);

    // ---- fused softmax + aggregation (wave per node) ----
    hipLaunchKernelGGL(gat_agg_kernel, dim3((N + 3) / 4), blk, 0, stream,
                       rowptr, col, qkv, agg, N);

    // ---- out-projection + bias + fp32 src residual -> y1 bf16 ----
    hipLaunchKernelGGL((gemm_v2_kernel<0, 3, 128, 32>), gG, blk, 0, stream,
                       agg, woutb, out_b, src, nullptr, y1b, N);

    // ---- BN1 stats ----
    dim3 gS((N + 255) / 256);
    hipLaunchKernelGGL(bn_stats_bf16_kernel, gS, blk, 0, stream, y1b, N, stats1);
    hipLaunchKernelGGL(bn_finalize_kernel, dim3(1), dim3(128), 0, stream, stats1, g1, b1, N);

    // ---- FFN: lin1 applies BN1 on A-load, leaky epi -> hid bf16 ----
    hipLaunchKernelGGL((gemm_v2_kernel<2, 2, 128, 128>), gG, blk, 0, stream,
                       y1b, w1b, lin1_b, nullptr, stats1, hid, N);
    // ---- lin2 + bias + BN1(y1) residual -> y2 bf16 ----
    hipLaunchKernelGGL((gemm_v2_kernel<0, 4, 512, 32>), gG, blk, 0, stream,
                       hid, w2b, lin2_b, y1b, stats1, y2b, N);

    // ---- BN2 -> d_out fp32 ----
    hipLaunchKernelGGL(bn_stats_bf16_kernel, gS, blk, 0, stream, y2b, N, stats2);
    hipLaunchKernelGGL(bn_finalize_kernel, dim3(1), dim3(128), 0, stream, stats2, g2, b2, N);
    int total4 = N * D / 4;
    hipLaunchKernelGGL(bn_apply_out_kernel, dim3((total4 + 255) / 256), blk, 0, stream,
                       y2b, stats2, (float*)d_out, total4);
}